// Round 9
// baseline (22638.029 us; speedup 1.0000x reference)
//
#include <hip/hip_runtime.h>

#define S 1024
#define NOBS 4096
#define TSTEPS 8192
#define NWG 8     // one WG per XCD (round-robin dispatch); all trivially co-resident
#define COLS 128  // output columns per WG
#define NTHR 512  // 8 waves
#define NWAVE 8
#define CPW 16    // columns per wave

#define AGENT __HIP_MEMORY_SCOPE_AGENT

typedef __attribute__((ext_vector_type(2))) _Float16 half2v;
typedef __attribute__((ext_vector_type(2))) unsigned short ushort2v;

__device__ __forceinline__ float wmaxred(float v) {
#pragma unroll
  for (int off = 32; off > 0; off >>= 1) v = fmaxf(v, __shfl_xor(v, off, 64));
  return v;
}
__device__ __forceinline__ float wsumred(float v) {
#pragma unroll
  for (int off = 32; off > 0; off >>= 1) v += __shfl_xor(v, off, 64);
  return v;
}

__device__ __forceinline__ float f16v(unsigned short b) {
  return (float)__builtin_bit_cast(_Float16, b);
}
__device__ __forceinline__ unsigned short f16b(float f) {
  return __builtin_bit_cast(unsigned short, (_Float16)f);
}

// Self-validating poll of one u64 (2 tagged u32 slots), agent scope (LLC path —
// the best-measured transport: r4 = 1.54 us/step vs sc0/XCD >= 2.0).
__device__ __forceinline__ unsigned long long poll1(const unsigned long long* a,
                                                    unsigned tag) {
  const unsigned long long pat =
      ((unsigned long long)tag << 16) | ((unsigned long long)tag << 48);
  const unsigned long long msk = 0xFFFF0000FFFF0000ULL;
  unsigned long long w;
  do {
    w = __hip_atomic_load(a, __ATOMIC_RELAXED, AGENT);
  } while ((w & msk) != pat);
  return w;
}

// One-time: Et[j][i] = exp(trans[i][j])  (transposed, fp16) via LDS tile transpose.
__global__ void prep_E(const float* __restrict__ trans, _Float16* __restrict__ Et) {
  __shared__ float tile[32][33];
  const int tx = threadIdx.x, ty = threadIdx.y;
  const int bi = blockIdx.y, bj = blockIdx.x;
  tile[ty][tx] = trans[(size_t)(bi * 32 + ty) * S + bj * 32 + tx];
  __syncthreads();
  Et[(size_t)(bj * 32 + ty) * S + bi * 32 + tx] = (_Float16)__expf(tile[tx][ty]);
}

// One-time: emitT[o][j] = emit[j][o] (fp16): per step all 1024 emit values are
// one contiguous 2 KB row (L2/LLC-resident) instead of 1024 scattered lines.
__global__ void prep_emitT(const float* __restrict__ emit, _Float16* __restrict__ emitT) {
  __shared__ float tile[32][33];
  const int tx = threadIdx.x, ty = threadIdx.y;
  const int bj = blockIdx.y, bo = blockIdx.x;
  tile[ty][tx] = emit[(size_t)(bj * 32 + ty) * NOBS + bo * 32 + tx];
  __syncthreads();
  emitT[(size_t)(bo * 32 + ty) * S + bj * 32 + tx] = (_Float16)tile[tx][ty];
}

// One-time: r0 = start + emit[:, obs[0]] packed {tag=0|fp16} into buffer 0.
__global__ void hmm_init(const int* __restrict__ obs, const float* __restrict__ start,
                         const float* __restrict__ emit, unsigned* rbuf) {
  const int tid = threadIdx.x;  // 1024 threads
  const float r = start[tid] + emit[(size_t)tid * NOBS + obs[0]];
  __hip_atomic_store(&rbuf[tid], (unsigned)f16b(r), __ATOMIC_RELAXED, AGENT);
}

__global__ __launch_bounds__(NTHR, 2) void hmm_main(
    const int* __restrict__ obs, const _Float16* __restrict__ emitT,
    const _Float16* __restrict__ Et, unsigned* rbuf, float* __restrict__ out) {
  __shared__ unsigned sp[2][S / 2];  // p packed half2, double-buffered (4 KB)
  __shared__ float wred[NWAVE];
  const int tid = threadIdx.x;
  const int lane = tid & 63;
  const int wave = tid >> 6;
  const int wg = blockIdx.x;
  const int c0 = wg * COLS + wave * CPW;  // this wave's 16 output columns

  // E fragments in registers: er[c][k] covers sources {k*128+2*lane, +1} for
  // column c0+c. 128 packed-fp16 VGPRs/thread.
  half2v er[CPW][8];
#pragma unroll
  for (int c = 0; c < CPW; ++c)
#pragma unroll
    for (int k = 0; k < 8; ++k)
      er[c][k] = *(const half2v*)(Et + (size_t)(c0 + c) * S + k * 128 + lane * 2);

  // emitT prefetch pipeline: 4 steps per fetch, double-buffered. Lane L carries
  // e for step-offset L>>4 (0..3), column c0+(L&15); consumed 4..8 steps later.
  const int pfoff = lane >> 4;
  const int pfcol = c0 + (lane & 15);
  float curE = (float)emitT[(size_t)obs[1 + pfoff] * S + pfcol];
  float nxtE = (float)emitT[(size_t)obs[5 + pfoff] * S + pfcol];

  unsigned long long* const b0 = (unsigned long long*)rbuf;        // even t
  unsigned long long* const b1 = (unsigned long long*)(rbuf + S);  // odd t

  // Preamble: fresh m = max(r_0), bit-identical in every thread/WG.
  {
    const unsigned long long w = poll1(b0 + tid, 0u);
    const float wm =
        wmaxred(fmaxf(f16v((unsigned short)w), f16v((unsigned short)(w >> 32))));
    if (lane == 0) wred[wave] = wm;
  }
  __syncthreads();
  float m = wred[0];
#pragma unroll
  for (int k = 1; k < NWAVE; ++k) m = fmaxf(m, wred[k]);

  double c = 0.0;  // accumulated scale offset; identical in every thread
  for (int t = 1; t < TSTEPS; ++t) {
    const int s = (t - 1) & 3;
    if (s == 0 && t > 1) {  // rotate prefetch buffers, fetch group [t+4, t+8)
      curE = nxtE;
      const int oi = obs[min(t + 4 + pfoff, TSTEPS - 1)];
      nxtE = (float)emitT[(size_t)oi * S + pfcol];
    }
    // e for this lane's column c0+(lane&15) at step t — one shuffle, no memory
    const float ecol = __shfl(curE, s * 16 + (lane & 15));

    // poll own u64 of r_{t-1} (slots 2*tid, 2*tid+1); 512 threads cover all 1024
    const unsigned long long w = poll1(((t & 1) ? b0 : b1) + tid, (unsigned)(t - 1));
    half2v ph;
    ph[0] = (_Float16)__expf(f16v((unsigned short)w) - m);
    ph[1] = (_Float16)__expf(f16v((unsigned short)(w >> 32)) - m);
    sp[t & 1][tid] = __builtin_bit_cast(unsigned, ph);
    __syncthreads();  // the only barrier per step

    // dot: 8 conflict-free LDS b32 reads, 128 fdot2; packed max(p) alongside
    const unsigned* pb = sp[t & 1];
    float a[CPW];
#pragma unroll
    for (int ci = 0; ci < CPW; ++ci) a[ci] = 0.f;
    ushort2v mx = {0, 0};
#pragma unroll
    for (int k = 0; k < 8; ++k) {
      const unsigned pw = pb[k * 64 + lane];
      mx = __builtin_elementwise_max(mx, __builtin_bit_cast(ushort2v, pw));
      const half2v pv = __builtin_bit_cast(half2v, pw);
#pragma unroll
      for (int ci = 0; ci < CPW; ++ci)
        a[ci] = __builtin_amdgcn_fdot2(pv, er[ci][k], a[ci], false);
    }

    // transpose-reduce: 4 butterflies x 16 accs -> 15-select -> 2 butterflies.
    // Ends with lane L holding the full sum for column c0+(L&15).
#pragma unroll
    for (int off = 1; off <= 8; off <<= 1) {
#pragma unroll
      for (int ci = 0; ci < CPW; ++ci) a[ci] += __shfl_xor(a[ci], off, 64);
    }
    const int idx = lane & 15;
    float p01 = (idx & 1) ? a[1] : a[0], p23 = (idx & 1) ? a[3] : a[2];
    float p45 = (idx & 1) ? a[5] : a[4], p67 = (idx & 1) ? a[7] : a[6];
    float p89 = (idx & 1) ? a[9] : a[8], pab = (idx & 1) ? a[11] : a[10];
    float pcd = (idx & 1) ? a[13] : a[12], pef = (idx & 1) ? a[15] : a[14];
    float q0 = (idx & 2) ? p23 : p01, q1 = (idx & 2) ? p67 : p45;
    float q2 = (idx & 2) ? pab : p89, q3 = (idx & 2) ? pef : pcd;
    float u0 = (idx & 4) ? q1 : q0, u1 = (idx & 4) ? q3 : q2;
    float v = (idx & 8) ? u1 : u0;
    v += __shfl_xor(v, 16, 64);
    v += __shfl_xor(v, 32, 64);

    // publish: lanes 0..15 store their own tagged u32 (coalesced 64 B)
    const unsigned myw = ((unsigned)t << 16) | f16b(__logf(v) + ecol);
    if (lane < CPW)
      __hip_atomic_store(&rbuf[(t & 1) * S + c0 + lane], myw, __ATOMIC_RELAXED, AGENT);

    // off the critical path: scale bookkeeping and next step's stale m
    c += (double)m;
#pragma unroll
    for (int off = 32; off > 0; off >>= 1) {
      const unsigned o2 = __shfl_xor(__builtin_bit_cast(unsigned, mx), off, 64);
      mx = __builtin_elementwise_max(mx, __builtin_bit_cast(ushort2v, o2));
    }
    const unsigned short ms = mx[0] > mx[1] ? mx[0] : mx[1];  // positive fp16: bit order = value order
    m += __logf(f16v(ms));  // m = max(r_{t-1}); bit-identical in every wave/WG
  }

  // Final logsumexp over r_{T-1} by WG 0, wave 0 (8 u64/lane covers all 1024).
  if (wg == 0 && wave == 0) {
    const unsigned long long* src = b1 + lane * 8;  // 8191 is odd
    float v[16];
#pragma unroll
    for (int j = 0; j < 8; ++j) {
      const unsigned long long w = poll1(&src[j], TSTEPS - 1);
      v[2 * j] = f16v((unsigned short)w);
      v[2 * j + 1] = f16v((unsigned short)(w >> 32));
    }
    float g = -1e30f;
#pragma unroll
    for (int j = 0; j < 16; ++j) g = fmaxf(g, v[j]);
    g = wmaxred(g);
    float s = 0.f;
#pragma unroll
    for (int j = 0; j < 16; ++j) s += __expf(v[j] - g);
    s = wsumred(s);
    if (lane == 0) out[0] = (float)(c + (double)g + (double)__logf(s));
  }
}

extern "C" void kernel_launch(void* const* d_in, const int* in_sizes, int n_in,
                              void* d_out, int out_size, void* d_ws, size_t ws_size,
                              hipStream_t stream) {
  const int* obs = (const int*)d_in[0];
  const float* start = (const float*)d_in[1];
  const float* trans = (const float*)d_in[2];
  const float* emit = (const float*)d_in[3];

  // ws: 0: rbuf[2][1024] u32 (8 KB) | 16384: Et (2 MB) | +2M: emitT (8 MB)
  unsigned* rbuf = (unsigned*)d_ws;
  _Float16* Et = (_Float16*)((char*)d_ws + 16384);
  _Float16* emitT = (_Float16*)((char*)d_ws + 16384 + (size_t)2 * 1024 * 1024);

  prep_E<<<dim3(32, 32), dim3(32, 32), 0, stream>>>(trans, Et);
  prep_emitT<<<dim3(NOBS / 32, S / 32), dim3(32, 32), 0, stream>>>(emit, emitT);
  hmm_init<<<1, S, 0, stream>>>(obs, start, emit, rbuf);
  hmm_main<<<NWG, NTHR, 0, stream>>>(obs, emitT, Et, rbuf, (float*)d_out);
}

// Round 10
// 13158.751 us; speedup vs baseline: 1.7204x; 1.7204x over previous
//
#include <hip/hip_runtime.h>

#define S 1024
#define NOBS 4096
#define TSTEPS 8192
#define NWG 64    // r4-proven topology: 64 WGs, 16 cols each
#define COLS 16
#define NTHR 512  // 8 waves
#define NWAVE 8

#define AGENT __HIP_MEMORY_SCOPE_AGENT

typedef __attribute__((ext_vector_type(2))) _Float16 half2v;
typedef __attribute__((ext_vector_type(2))) unsigned short ushort2v;

__device__ __forceinline__ float wmaxred(float v) {
#pragma unroll
  for (int off = 32; off > 0; off >>= 1) v = fmaxf(v, __shfl_xor(v, off, 64));
  return v;
}
__device__ __forceinline__ float wsumred(float v) {
#pragma unroll
  for (int off = 32; off > 0; off >>= 1) v += __shfl_xor(v, off, 64);
  return v;
}

__device__ __forceinline__ float f16v(unsigned short b) {
  return (float)__builtin_bit_cast(_Float16, b);
}
__device__ __forceinline__ unsigned short f16b(float f) {
  return __builtin_bit_cast(unsigned short, (_Float16)f);
}

// 4-deep pipelined poll of one u64: four outstanding loads per iteration give
// 4 samples per LLC-latency period (compiler emits the vmcnt(3..0) staircase),
// cutting detect quantization ~4x vs the single-load spin.
__device__ __forceinline__ unsigned long long poll1(const unsigned long long* a,
                                                    unsigned tag) {
  const unsigned long long pat =
      ((unsigned long long)tag << 16) | ((unsigned long long)tag << 48);
  const unsigned long long msk = 0xFFFF0000FFFF0000ULL;
  for (;;) {
    const unsigned long long w0 = __hip_atomic_load(a, __ATOMIC_RELAXED, AGENT);
    const unsigned long long w1 = __hip_atomic_load(a, __ATOMIC_RELAXED, AGENT);
    const unsigned long long w2 = __hip_atomic_load(a, __ATOMIC_RELAXED, AGENT);
    const unsigned long long w3 = __hip_atomic_load(a, __ATOMIC_RELAXED, AGENT);
    if ((w0 & msk) == pat) return w0;
    if ((w1 & msk) == pat) return w1;
    if ((w2 & msk) == pat) return w2;
    if ((w3 & msk) == pat) return w3;
  }
}

// One-time: Et[j][i] = exp(trans[i][j])  (transposed, fp16) via LDS tile transpose.
__global__ void prep_E(const float* __restrict__ trans, _Float16* __restrict__ Et) {
  __shared__ float tile[32][33];
  const int tx = threadIdx.x, ty = threadIdx.y;
  const int bi = blockIdx.y, bj = blockIdx.x;
  tile[ty][tx] = trans[(size_t)(bi * 32 + ty) * S + bj * 32 + tx];
  __syncthreads();
  Et[(size_t)(bj * 32 + ty) * S + bi * 32 + tx] = (_Float16)__expf(tile[tx][ty]);
}

// One-time: emitT[o][j] = emit[j][o] (fp16): per step all 1024 emit values are
// one contiguous 2 KB row (16 lines, cache-resident) instead of 1024 lines.
__global__ void prep_emitT(const float* __restrict__ emit, _Float16* __restrict__ emitT) {
  __shared__ float tile[32][33];
  const int tx = threadIdx.x, ty = threadIdx.y;
  const int bj = blockIdx.y, bo = blockIdx.x;
  tile[ty][tx] = emit[(size_t)(bj * 32 + ty) * NOBS + bo * 32 + tx];
  __syncthreads();
  emitT[(size_t)(bo * 32 + ty) * S + bj * 32 + tx] = (_Float16)tile[tx][ty];
}

// One-time: r0 = start + emit[:, obs[0]] packed {tag=0|fp16} into buffer 0.
__global__ void hmm_init(const int* __restrict__ obs, const float* __restrict__ start,
                         const float* __restrict__ emit, unsigned* rbuf) {
  const int tid = threadIdx.x;  // 1024 threads
  const float r = start[tid] + emit[(size_t)tid * NOBS + obs[0]];
  __hip_atomic_store(&rbuf[tid], (unsigned)f16b(r), __ATOMIC_RELAXED, AGENT);
}

__global__ __launch_bounds__(NTHR) void hmm_main(
    const int* __restrict__ obs, const _Float16* __restrict__ emitT,
    const _Float16* __restrict__ Et, unsigned* rbuf, float* __restrict__ out) {
  __shared__ unsigned sp[2][S / 2];  // p packed half2, double-buffered (4 KB)
  __shared__ float wred[NWAVE];
  const int tid = threadIdx.x;
  const int lane = tid & 63;
  const int wave = tid >> 6;
  const int wg = blockIdx.x;
  // XCD swizzle (r4-proven): each XCD's 8 WGs own 4 contiguous cachelines.
  const int chunk = (wg & 7) * 8 + (wg >> 3);
  const int c0 = chunk * COLS + wave * 2;  // this wave's two output columns

  // E fragments, packed fp16: er[cc][k] = E[sources k*128+2*lane,+1][col c0+cc]
  half2v er[2][8];
#pragma unroll
  for (int cc = 0; cc < 2; ++cc)
#pragma unroll
    for (int k = 0; k < 8; ++k)
      er[cc][k] = *(const half2v*)(Et + (size_t)(c0 + cc) * S + k * 128 + lane * 2);

  // emitT prefetch pipeline: 8 steps/fetch, double-buffered. Lane L (<16)
  // carries e for step-offset L>>1, column c0+(L&1); consumed 8..16 steps later.
  const int pfoff = (lane >> 1) & 7;
  const int pfcol = c0 + (lane & 1);
  float curE = (float)emitT[(size_t)obs[1 + pfoff] * S + pfcol];
  float nxtE = (float)emitT[(size_t)obs[9 + pfoff] * S + pfcol];

  unsigned long long* const b0 = (unsigned long long*)rbuf;        // even t
  unsigned long long* const b1 = (unsigned long long*)(rbuf + S);  // odd t

  // Preamble: fresh m = max(r_0), bit-identical in every thread/WG.
  {
    const unsigned long long w = poll1(b0 + tid, 0u);
    const float wm =
        wmaxred(fmaxf(f16v((unsigned short)w), f16v((unsigned short)(w >> 32))));
    if (lane == 0) wred[wave] = wm;
  }
  __syncthreads();
  float m = wred[0];
#pragma unroll
  for (int k = 1; k < NWAVE; ++k) m = fmaxf(m, wred[k]);

  double c = 0.0;  // accumulated scale offset; identical in every thread
  for (int t = 1; t < TSTEPS; ++t) {
    const int s = (t - 1) & 7;
    if (s == 0 && t > 1) {  // rotate prefetch buffers, fetch group [t+8, t+16)
      curE = nxtE;
      const int oi = obs[min(t + 8 + pfoff, TSTEPS - 1)];
      nxtE = (float)emitT[(size_t)oi * S + pfcol];
    }
    // e for column c0+(lane&1) at step t — one shuffle, no memory
    const float ecol = __shfl(curE, (s << 1) | (lane & 1));

    // poll own u64 of r_{t-1} (slots 2*tid, 2*tid+1); 512 threads cover all 1024
    const unsigned long long w = poll1(((t & 1) ? b0 : b1) + tid, (unsigned)(t - 1));
    half2v ph;
    ph[0] = (_Float16)__expf(f16v((unsigned short)w) - m);
    ph[1] = (_Float16)__expf(f16v((unsigned short)(w >> 32)) - m);
    sp[t & 1][tid] = __builtin_bit_cast(unsigned, ph);
    __syncthreads();  // the only barrier per step

    // dot: 8 conflict-free LDS b32 reads, 16 fdot2; packed max(p) alongside
    const unsigned* pb = sp[t & 1];
    float a0 = 0.f, a1 = 0.f;
    ushort2v mx = {0, 0};
#pragma unroll
    for (int k = 0; k < 8; ++k) {
      const unsigned pw = pb[k * 64 + lane];
      mx = __builtin_elementwise_max(mx, __builtin_bit_cast(ushort2v, pw));
      const half2v pv = __builtin_bit_cast(half2v, pw);
      a0 = __builtin_amdgcn_fdot2(pv, er[0][k], a0, false);
      a1 = __builtin_amdgcn_fdot2(pv, er[1][k], a1, false);
    }
    // transpose-reduce: 1 butterfly x 2 accs -> select -> 5 butterflies (8 ops).
    a0 += __shfl_xor(a0, 1, 64);
    a1 += __shfl_xor(a1, 1, 64);
    float v = (lane & 1) ? a1 : a0;
#pragma unroll
    for (int off = 2; off <= 32; off <<= 1) v += __shfl_xor(v, off, 64);

    // publish: lanes 0,1 store adjacent tagged u32 (one coalesced 8-B txn);
    // logs run in parallel on the two lanes.
    if (lane < 2) {
      const unsigned myw = ((unsigned)t << 16) | f16b(__logf(v) + ecol);
      __hip_atomic_store(&rbuf[(t & 1) * S + c0 + lane], myw, __ATOMIC_RELAXED, AGENT);
    }

    // off the critical path: scale bookkeeping and next step's stale m
    c += (double)m;
#pragma unroll
    for (int off = 32; off > 0; off >>= 1) {
      const unsigned o2 = __shfl_xor(__builtin_bit_cast(unsigned, mx), off, 64);
      mx = __builtin_elementwise_max(mx, __builtin_bit_cast(ushort2v, o2));
    }
    const unsigned short ms = mx[0] > mx[1] ? mx[0] : mx[1];  // positive fp16: bit order = value order
    m += __logf(f16v(ms));  // m = max(r_{t-1}); bit-identical in every wave/WG
  }

  // Final logsumexp over r_{T-1} by WG 0, wave 0 (8 u64/lane covers all 1024).
  if (wg == 0 && wave == 0) {
    const unsigned long long* src = b1 + lane * 8;  // 8191 is odd
    float v[16];
#pragma unroll
    for (int j = 0; j < 8; ++j) {
      const unsigned long long w = poll1(&src[j], TSTEPS - 1);
      v[2 * j] = f16v((unsigned short)w);
      v[2 * j + 1] = f16v((unsigned short)(w >> 32));
    }
    float g = -1e30f;
#pragma unroll
    for (int j = 0; j < 16; ++j) g = fmaxf(g, v[j]);
    g = wmaxred(g);
    float s = 0.f;
#pragma unroll
    for (int j = 0; j < 16; ++j) s += __expf(v[j] - g);
    s = wsumred(s);
    if (lane == 0) out[0] = (float)(c + (double)g + (double)__logf(s));
  }
}

extern "C" void kernel_launch(void* const* d_in, const int* in_sizes, int n_in,
                              void* d_out, int out_size, void* d_ws, size_t ws_size,
                              hipStream_t stream) {
  const int* obs = (const int*)d_in[0];
  const float* start = (const float*)d_in[1];
  const float* trans = (const float*)d_in[2];
  const float* emit = (const float*)d_in[3];

  // ws: 0: rbuf[2][1024] u32 (8 KB) | 16384: Et (2 MB) | +2M: emitT (8 MB)
  unsigned* rbuf = (unsigned*)d_ws;
  _Float16* Et = (_Float16*)((char*)d_ws + 16384);
  _Float16* emitT = (_Float16*)((char*)d_ws + 16384 + (size_t)2 * 1024 * 1024);

  prep_E<<<dim3(32, 32), dim3(32, 32), 0, stream>>>(trans, Et);
  prep_emitT<<<dim3(NOBS / 32, S / 32), dim3(32, 32), 0, stream>>>(emit, emitT);
  hmm_init<<<1, S, 0, stream>>>(obs, start, emit, rbuf);
  hmm_main<<<NWG, NTHR, 0, stream>>>(obs, emitT, Et, rbuf, (float*)d_out);
}